// Round 3
// baseline (103.032 us; speedup 1.0000x reference)
//
#include <hip/hip_runtime.h>

#define BS 4
#define DM 1024
#define LL 2048
#define NS 64
#define CC 32        // chunks; state ws = CC*BS*NS*DM*4 = 32 MB (fits ws per round-1)
#define TC 64        // chunk length = LL/CC
#define ROWS 256
#define PADS 65      // odd stride: compute reads bank=(tid+t)%32 -> 2-way (free)

// ---------------- pass 1: chunk-local final states (zero init) ----------------
__global__ __launch_bounds__(256, 2) void ssm_pass1(const float* __restrict__ u,
                                                    const float* __restrict__ A,
                                                    float* __restrict__ s) {
    __shared__ float tile[ROWS * PADS];
    const int tid = threadIdx.x;
    const int bx  = blockIdx.x;
    const int c   = bx & (CC - 1);
    const int rem = bx >> 5;
    const int b   = rem & (BS - 1);
    const int d0  = (rem >> 2) * ROWS;

    // stage u tile (ROWS x TC) with float4 global loads
    {
        const float* ubase = u + ((size_t)(b * DM + d0) * LL + c * TC);
#pragma unroll
        for (int k = 0; k < 16; ++k) {
            const int idx = tid + k * 256;
            const int r   = idx >> 4;          // 16 float4 per row of 64
            const int t4  = (idx & 15) * 4;
            const float4 v = *reinterpret_cast<const float4*>(ubase + (size_t)r * LL + t4);
            float* dst = &tile[r * PADS + t4];
            dst[0] = v.x; dst[1] = v.y; dst[2] = v.z; dst[3] = v.w;
        }
    }

    // pin a[] into VGPRs (compiler can't hold 64 uniform floats in SGPRs -> re-loads)
    float a[NS];
#pragma unroll
    for (int i = 0; i < NS; ++i) {
        float av = A[i * (NS + 1)];
        asm volatile("" : "+v"(av));
        a[i] = av;
    }

    __syncthreads();

    float g[NS];
#pragma unroll
    for (int i = 0; i < NS; ++i) g[i] = 0.f;
    const float* row = &tile[tid * PADS];
    for (int t = 0; t < TC; ++t) {
        const float uv = row[t];
#pragma unroll
        for (int i = 0; i < NS; ++i) g[i] = fmaf(a[i], g[i], uv);
    }
    const int d = d0 + tid;
#pragma unroll
    for (int i = 0; i < NS; ++i)
        s[(((size_t)c * BS + b) * NS + i) * DM + d] = g[i];
}

// ---------------- combine: local end-states -> true chunk-initial states (in place) ----------------
__global__ void ssm_combine(const float* __restrict__ A, float* __restrict__ s) {
    const int tid = blockIdx.x * blockDim.x + threadIdx.x;  // B*N*D threads
    const int d   = tid & (DM - 1);
    const int rem = tid >> 10;
    const int i   = rem & (NS - 1);
    const int b   = rem >> 6;

    const float a = A[i * (NS + 1)];
    float aT = a;                 // a^TC, TC=64 -> 6 squarings
#pragma unroll
    for (int j = 0; j < 6; ++j) aT *= aT;

    float run = 0.f;
    for (int c = 0; c < CC; ++c) {
        const size_t idx = (((size_t)c * BS + b) * NS + i) * DM + d;
        const float sl = s[idx];
        s[idx] = run;             // true initial state of chunk c
        run = fmaf(aT, run, sl);
    }
}

// ---------------- pass 2: recurrence with true init, produce y ----------------
__global__ __launch_bounds__(256, 2) void ssm_pass2(const float* __restrict__ u,
                                                    const float* __restrict__ A,
                                                    const float* __restrict__ Bv,
                                                    const float* __restrict__ Cv,
                                                    const float* __restrict__ s,
                                                    float* __restrict__ y) {
    __shared__ float tile[ROWS * PADS];
    const int tid = threadIdx.x;
    const int bx  = blockIdx.x;
    const int c   = bx & (CC - 1);
    const int rem = bx >> 5;
    const int b   = rem & (BS - 1);
    const int d0  = (rem >> 2) * ROWS;

    // stage u tile with float4 global loads
    {
        const float* ubase = u + ((size_t)(b * DM + d0) * LL + c * TC);
#pragma unroll
        for (int k = 0; k < 16; ++k) {
            const int idx = tid + k * 256;
            const int r   = idx >> 4;
            const int t4  = (idx & 15) * 4;
            const float4 v = *reinterpret_cast<const float4*>(ubase + (size_t)r * LL + t4);
            float* dst = &tile[r * PADS + t4];
            dst[0] = v.x; dst[1] = v.y; dst[2] = v.z; dst[3] = v.w;
        }
    }

    // pin a[], w[] into VGPRs
    float a[NS], w[NS];
#pragma unroll
    for (int i = 0; i < NS; ++i) {
        float av = A[i * (NS + 1)];
        float wv = Bv[i] * Cv[i];
        asm volatile("" : "+v"(av), "+v"(wv));
        a[i] = av; w[i] = wv;
    }

    float g[NS];
    const int d = d0 + tid;
#pragma unroll
    for (int i = 0; i < NS; ++i)
        g[i] = s[(((size_t)c * BS + b) * NS + i) * DM + d];

    __syncthreads();

    float* row = &tile[tid * PADS];
    for (int t = 0; t < TC; ++t) {
        const float uv = row[t];
        float y0 = 0.f, y1 = 0.f, y2 = 0.f, y3 = 0.f;
#pragma unroll
        for (int i = 0; i < NS; i += 4) {
            g[i + 0] = fmaf(a[i + 0], g[i + 0], uv); y0 = fmaf(w[i + 0], g[i + 0], y0);
            g[i + 1] = fmaf(a[i + 1], g[i + 1], uv); y1 = fmaf(w[i + 1], g[i + 1], y1);
            g[i + 2] = fmaf(a[i + 2], g[i + 2], uv); y2 = fmaf(w[i + 2], g[i + 2], y2);
            g[i + 3] = fmaf(a[i + 3], g[i + 3], uv); y3 = fmaf(w[i + 3], g[i + 3], y3);
        }
        row[t] = (y0 + y1) + (y2 + y3);   // overwrite consumed u slot with y
    }
    __syncthreads();

    // coalesced float4 writeout of y from LDS
    {
        float* ybase = y + ((size_t)(b * DM + d0) * LL + c * TC);
#pragma unroll
        for (int k = 0; k < 16; ++k) {
            const int idx = tid + k * 256;
            const int r   = idx >> 4;
            const int t4  = (idx & 15) * 4;
            const float* sp = &tile[r * PADS + t4];
            const float4 v = make_float4(sp[0], sp[1], sp[2], sp[3]);
            *reinterpret_cast<float4*>(ybase + (size_t)r * LL + t4) = v;
        }
    }
}

extern "C" void kernel_launch(void* const* d_in, const int* in_sizes, int n_in,
                              void* d_out, int out_size, void* d_ws, size_t ws_size,
                              hipStream_t stream) {
    const float* u  = (const float*)d_in[0];
    const float* A  = (const float*)d_in[1];
    const float* Bv = (const float*)d_in[2];
    const float* Cv = (const float*)d_in[3];
    float* y = (float*)d_out;
    float* s = (float*)d_ws;

    const int nblocks = CC * BS * (DM / ROWS);   // 512
    ssm_pass1<<<nblocks, 256, 0, stream>>>(u, A, s);
    ssm_combine<<<(BS * NS * DM) / 256, 256, 0, stream>>>(A, s);
    ssm_pass2<<<nblocks, 256, 0, stream>>>(u, A, Bv, Cv, s, y);
}

// Round 4
// 68.200 us; speedup vs baseline: 1.5107x; 1.5107x over previous
//
#include <hip/hip_runtime.h>

#define BS 4
#define DM 1024
#define LL 2048
#define NS 64
#define CC 32        // chunks; state ws = CC*BS*NS*DM*4 = 32 MB (fits: round-1 ran C=32)
#define TC 64        // chunk length = LL/CC
#define ROWS 128     // d-rows per block
#define PADS 65      // odd stride -> (d+t)%32 banks, conflict-free
#define NSG 32       // states per lane-group (lane&1 picks the group)

// ---------------- pass 1: chunk-local final states (zero init) ----------------
__global__ __launch_bounds__(256, 3) void ssm_pass1(const float* __restrict__ u,
                                                    const float* __restrict__ A,
                                                    float* __restrict__ s) {
    __shared__ float tile[ROWS * PADS];
    const int tid  = threadIdx.x;
    const int bx   = blockIdx.x;
    const int c    = bx & (CC - 1);
    const int rem  = bx >> 5;
    const int b    = rem & (BS - 1);
    const int d0   = (rem >> 2) * ROWS;
    const int wave = tid >> 6;
    const int lane = tid & 63;
    const int dl   = 32 * wave + (lane >> 1);   // d-row within block
    const int grp  = lane & 1;                  // state group
    const int ib   = NSG * grp;                 // first state index

    // stage u tile (ROWS x TC), float4 global loads, scalar LDS writes (2-way = free)
    {
        const float* ubase = u + ((size_t)(b * DM + d0) * LL + c * TC);
#pragma unroll
        for (int k = 0; k < 8; ++k) {
            const int idx = tid + k * 256;
            const int r   = idx >> 4;           // 16 float4 per row of TC=64
            const int t4  = (idx & 15) * 4;
            const float4 v = *reinterpret_cast<const float4*>(ubase + (size_t)r * LL + t4);
            float* dst = &tile[r * PADS + t4];
            dst[0] = v.x; dst[1] = v.y; dst[2] = v.z; dst[3] = v.w;
        }
    }

    // params: divergent (grp-dependent) addresses -> guaranteed VGPR-resident
    float a[NSG];
#pragma unroll
    for (int j = 0; j < NSG; ++j) a[j] = A[(ib + j) * (NS + 1)];

    float g[NSG];
#pragma unroll
    for (int j = 0; j < NSG; ++j) g[j] = 0.f;

    __syncthreads();

    const float* row = &tile[dl * PADS];
#pragma unroll 2
    for (int t = 0; t < TC; ++t) {
        const float uv = row[t];
#pragma unroll
        for (int j = 0; j < NSG; ++j) g[j] = fmaf(a[j], g[j], uv);
    }

    const int d = d0 + dl;
#pragma unroll
    for (int j = 0; j < NSG; ++j)
        s[(((size_t)c * BS + b) * NS + ib + j) * DM + d] = g[j];
}

// ---------------- combine: local end-states -> true chunk-initial states (in place) ----------------
__global__ void ssm_combine(const float* __restrict__ A, float* __restrict__ s) {
    const int tid = blockIdx.x * blockDim.x + threadIdx.x;  // B*N*D threads
    const int d   = tid & (DM - 1);
    const int rem = tid >> 10;
    const int i   = rem & (NS - 1);
    const int b   = rem >> 6;

    const float a = A[i * (NS + 1)];
    float aT = a;                 // a^TC, TC=64 -> 6 squarings
#pragma unroll
    for (int j = 0; j < 6; ++j) aT *= aT;

    float run = 0.f;
    for (int c = 0; c < CC; ++c) {
        const size_t idx = (((size_t)c * BS + b) * NS + i) * DM + d;
        const float sl = s[idx];
        s[idx] = run;             // true initial state of chunk c
        run = fmaf(aT, run, sl);
    }
}

// ---------------- pass 2: recurrence with true init, produce y ----------------
__global__ __launch_bounds__(256, 3) void ssm_pass2(const float* __restrict__ u,
                                                    const float* __restrict__ A,
                                                    const float* __restrict__ Bv,
                                                    const float* __restrict__ Cv,
                                                    const float* __restrict__ s,
                                                    float* __restrict__ y) {
    __shared__ float tile[ROWS * PADS];
    const int tid  = threadIdx.x;
    const int bx   = blockIdx.x;
    const int c    = bx & (CC - 1);
    const int rem  = bx >> 5;
    const int b    = rem & (BS - 1);
    const int d0   = (rem >> 2) * ROWS;
    const int wave = tid >> 6;
    const int lane = tid & 63;
    const int dl   = 32 * wave + (lane >> 1);
    const int grp  = lane & 1;
    const int ib   = NSG * grp;

    // stage u tile, float4 global loads
    {
        const float* ubase = u + ((size_t)(b * DM + d0) * LL + c * TC);
#pragma unroll
        for (int k = 0; k < 8; ++k) {
            const int idx = tid + k * 256;
            const int r   = idx >> 4;
            const int t4  = (idx & 15) * 4;
            const float4 v = *reinterpret_cast<const float4*>(ubase + (size_t)r * LL + t4);
            float* dst = &tile[r * PADS + t4];
            dst[0] = v.x; dst[1] = v.y; dst[2] = v.z; dst[3] = v.w;
        }
    }

    // divergent param loads -> VGPR-resident, no spill (96 array regs total)
    float a[NSG], w[NSG];
#pragma unroll
    for (int j = 0; j < NSG; ++j) {
        a[j] = A[(ib + j) * (NS + 1)];
        w[j] = Bv[ib + j] * Cv[ib + j];
    }

    // true chunk-initial states
    float g[NSG];
    const int d = d0 + dl;
#pragma unroll
    for (int j = 0; j < NSG; ++j)
        g[j] = s[(((size_t)c * BS + b) * NS + ib + j) * DM + d];

    __syncthreads();

    float* row = &tile[dl * PADS];
#pragma unroll 2
    for (int t = 0; t < TC; ++t) {
        const float uv = row[t];
        float y0 = 0.f, y1 = 0.f;
#pragma unroll
        for (int j = 0; j < NSG; j += 2) {
            g[j + 0] = fmaf(a[j + 0], g[j + 0], uv); y0 = fmaf(w[j + 0], g[j + 0], y0);
            g[j + 1] = fmaf(a[j + 1], g[j + 1], uv); y1 = fmaf(w[j + 1], g[j + 1], y1);
        }
        float yp = y0 + y1;
        yp += __shfl_xor(yp, 1, 64);   // combine the two state-halves of this d
        row[t] = yp;                   // both lanes write same value/addr (benign)
    }
    __syncthreads();

    // coalesced float4 writeout of y from LDS
    {
        float* ybase = y + ((size_t)(b * DM + d0) * LL + c * TC);
#pragma unroll
        for (int k = 0; k < 8; ++k) {
            const int idx = tid + k * 256;
            const int r   = idx >> 4;
            const int t4  = (idx & 15) * 4;
            const float* sp = &tile[r * PADS + t4];
            const float4 v = make_float4(sp[0], sp[1], sp[2], sp[3]);
            *reinterpret_cast<float4*>(ybase + (size_t)r * LL + t4) = v;
        }
    }
}

extern "C" void kernel_launch(void* const* d_in, const int* in_sizes, int n_in,
                              void* d_out, int out_size, void* d_ws, size_t ws_size,
                              hipStream_t stream) {
    const float* u  = (const float*)d_in[0];
    const float* A  = (const float*)d_in[1];
    const float* Bv = (const float*)d_in[2];
    const float* Cv = (const float*)d_in[3];
    float* y = (float*)d_out;
    float* s = (float*)d_ws;

    const int nblocks = CC * BS * (DM / ROWS);   // 1024
    ssm_pass1<<<nblocks, 256, 0, stream>>>(u, A, s);
    ssm_combine<<<(BS * NS * DM) / 256, 256, 0, stream>>>(A, s);
    ssm_pass2<<<nblocks, 256, 0, stream>>>(u, A, Bv, Cv, s, y);
}